// Round 2
// baseline (1566.865 us; speedup 1.0000x reference)
//
#include <hip/hip_runtime.h>
#include <hip/hip_bf16.h>

#define BB 2
#define TT 4096
#define DD 128
#define KK 256
#define NROW (BB*TT)    // 8192 rows
#define NELT (NROW*DD)  // 1048576 elements per [B,T,D] buffer

// ---------------- prep: k_hat = normalize(z@Wk+bk); memory_force (causal depthwise conv);
//                  zc = z; vsum = 0 ----------------
__global__ __launch_bounds__(128) void k_prep(
    const float* __restrict__ z, const float* __restrict__ ck, const float* __restrict__ cb,
    const float* __restrict__ Wk, const float* __restrict__ bk,
    float* __restrict__ kh, float* __restrict__ mf, float* __restrict__ zc,
    float* __restrict__ vsum)
{
  int row = blockIdx.x;
  int b = row >> 12;       // row / 4096
  int t = row & 4095;
  int d = threadIdx.x;
  __shared__ float zr[DD];
  __shared__ float red[DD];
  float zv = z[(size_t)row*DD + d];
  zr[d] = zv;
  zc[(size_t)row*DD + d] = zv;
  vsum[(size_t)row*DD + d] = 0.f;
  __syncthreads();
  float a = bk[d];
  #pragma unroll 4
  for (int i = 0; i < DD; i++) a = fmaf(zr[i], Wk[i*DD + d], a);
  red[d] = a*a; __syncthreads();
  for (int s = 64; s > 0; s >>= 1){ if (d < s) red[d] += red[d+s]; __syncthreads(); }
  float inv = 1.f / fmaxf(sqrtf(red[0]), 1e-8f);
  kh[(size_t)row*DD + d] = a * inv;
  // causal depthwise conv: mf[t,d] = cb[d] + sum_k z[t-(K-1)+k, d] * ck[k,d]
  float c = cb[d];
  const float* zb = z + (size_t)b*TT*DD;
  int kstart = (t >= KK-1) ? 0 : (KK-1-t);
  for (int k = kstart; k < KK; k++){
    int s = t - (KK-1) + k;
    c = fmaf(zb[(size_t)s*DD + d], ck[k*DD + d], c);
  }
  mf[(size_t)row*DD + d] = c;
}

// ---------------- q: q_hat = normalize(zc@Wq+bq); also zero att accumulator ----------------
__global__ __launch_bounds__(128) void k_q(
    const float* __restrict__ zc, const float* __restrict__ Wq, const float* __restrict__ bq,
    float* __restrict__ qh, float* __restrict__ att)
{
  int row = blockIdx.x; int d = threadIdx.x;
  __shared__ float zr[DD]; __shared__ float red[DD];
  float zv = zc[(size_t)row*DD + d]; zr[d] = zv;
  att[(size_t)row*DD + d] = 0.f;
  __syncthreads();
  float a = bq[d];
  #pragma unroll 4
  for (int i = 0; i < DD; i++) a = fmaf(zr[i], Wq[i*DD + d], a);
  red[d] = a*a; __syncthreads();
  for (int s = 64; s > 0; s >>= 1){ if (d < s) red[d] += red[d+s]; __syncthreads(); }
  float inv = 1.f / fmaxf(sqrtf(red[0]), 1e-8f);
  qh[(size_t)row*DD + d] = a * inv;
}

// ---------------- attn: att[t,:] += sum_{s<=t} sin(q_t . k_s) * k_s ----------------
#define TQ 32
#define NQT (TT/TQ)   // 128 query tiles per batch
#define NSEG 4
#define SEGT 32       // key tiles per segment (32 tiles * 32 keys = 1024 keys)

__global__ __launch_bounds__(256) void k_attn(
    const float* __restrict__ qh, const float* __restrict__ kh, float* __restrict__ att)
{
  int bid = blockIdx.x;
  int seg = bid & (NSEG-1);
  int qt  = (bid >> 2) & (NQT-1);
  int b   = bid >> 9;
  int kt0 = seg * SEGT;
  if (kt0 > qt) return;
  int kt1 = min(qt, kt0 + SEGT - 1);
  int t0 = qt * TQ;
  const float* qb = qh + (size_t)b*TT*DD;
  const float* kb = kh + (size_t)b*TT*DD;

  __shared__ __align__(16) float Qs[TQ][132];
  __shared__ __align__(16) float Ks[TQ][132];
  __shared__ __align__(16) float Ss[TQ][36];   // [key][query]

  int tid = threadIdx.x;
  // load Q tile (32 rows x 128 cols) as float4
  {
    const float4* src = (const float4*)(qb + (size_t)t0*DD);
    for (int i = tid; i < TQ*32; i += 256){
      int r = i >> 5, c = i & 31;
      ((float4*)&Qs[r][0])[c] = src[r*32 + c];
    }
  }
  float acc[4][4];
  #pragma unroll
  for (int i = 0; i < 4; i++)
    #pragma unroll
    for (int j = 0; j < 4; j++) acc[i][j] = 0.f;

  int rp = tid >> 4, cp = tid & 15;   // dots mapping: rows 2rp..2rp+1, cols 2cp..2cp+1
  int rg = tid >> 5, cg = tid & 31;   // acc mapping: rows 4rg..4rg+3, cols 4cg..4cg+3
  __syncthreads();

  for (int kt = kt0; kt <= kt1; kt++){
    int s0 = kt * TQ;
    {
      const float4* src = (const float4*)(kb + (size_t)s0*DD);
      for (int i = tid; i < TQ*32; i += 256){
        int r = i >> 5, c = i & 31;
        ((float4*)&Ks[r][0])[c] = src[r*32 + c];
      }
    }
    __syncthreads();
    // dots: 2x2 per thread
    {
      int r0 = 2*rp, c0 = 2*cp;
      const float4* q0 = (const float4*)&Qs[r0][0];
      const float4* q1 = (const float4*)&Qs[r0+1][0];
      const float4* k0 = (const float4*)&Ks[c0][0];
      const float4* k1 = (const float4*)&Ks[c0+1][0];
      float d00 = 0.f, d01 = 0.f, d10 = 0.f, d11 = 0.f;
      #pragma unroll 8
      for (int i = 0; i < 32; i++){
        float4 qa = q0[i], qc = q1[i], ka = k0[i], kc = k1[i];
        d00 = fmaf(qa.x, ka.x, d00); d00 = fmaf(qa.y, ka.y, d00);
        d00 = fmaf(qa.z, ka.z, d00); d00 = fmaf(qa.w, ka.w, d00);
        d01 = fmaf(qa.x, kc.x, d01); d01 = fmaf(qa.y, kc.y, d01);
        d01 = fmaf(qa.z, kc.z, d01); d01 = fmaf(qa.w, kc.w, d01);
        d10 = fmaf(qc.x, ka.x, d10); d10 = fmaf(qc.y, ka.y, d10);
        d10 = fmaf(qc.z, ka.z, d10); d10 = fmaf(qc.w, ka.w, d10);
        d11 = fmaf(qc.x, kc.x, d11); d11 = fmaf(qc.y, kc.y, d11);
        d11 = fmaf(qc.z, kc.z, d11); d11 = fmaf(qc.w, kc.w, d11);
      }
      int tq0 = t0 + r0;
      Ss[c0  ][r0  ] = (s0+c0   <= tq0  ) ? __sinf(d00) : 0.f;
      Ss[c0+1][r0  ] = (s0+c0+1 <= tq0  ) ? __sinf(d01) : 0.f;
      Ss[c0  ][r0+1] = (s0+c0   <= tq0+1) ? __sinf(d10) : 0.f;
      Ss[c0+1][r0+1] = (s0+c0+1 <= tq0+1) ? __sinf(d11) : 0.f;
    }
    __syncthreads();
    // accumulate: acc[r][c] += Ss[s][4rg+r] * Ks[s][4cg+c]
    #pragma unroll 8
    for (int s = 0; s < TQ; s++){
      float4 sv = ((const float4*)&Ss[s][0])[rg];
      float4 kv = ((const float4*)&Ks[s][0])[cg];
      acc[0][0] = fmaf(sv.x, kv.x, acc[0][0]);
      acc[0][1] = fmaf(sv.x, kv.y, acc[0][1]);
      acc[0][2] = fmaf(sv.x, kv.z, acc[0][2]);
      acc[0][3] = fmaf(sv.x, kv.w, acc[0][3]);
      acc[1][0] = fmaf(sv.y, kv.x, acc[1][0]);
      acc[1][1] = fmaf(sv.y, kv.y, acc[1][1]);
      acc[1][2] = fmaf(sv.y, kv.z, acc[1][2]);
      acc[1][3] = fmaf(sv.y, kv.w, acc[1][3]);
      acc[2][0] = fmaf(sv.z, kv.x, acc[2][0]);
      acc[2][1] = fmaf(sv.z, kv.y, acc[2][1]);
      acc[2][2] = fmaf(sv.z, kv.z, acc[2][2]);
      acc[2][3] = fmaf(sv.z, kv.w, acc[2][3]);
      acc[3][0] = fmaf(sv.w, kv.x, acc[3][0]);
      acc[3][1] = fmaf(sv.w, kv.y, acc[3][1]);
      acc[3][2] = fmaf(sv.w, kv.z, acc[3][2]);
      acc[3][3] = fmaf(sv.w, kv.w, acc[3][3]);
    }
    __syncthreads();
  }
  float* ab = att + ((size_t)b*TT + t0)*DD;
  #pragma unroll
  for (int ri = 0; ri < 4; ri++){
    int r = 4*rg + ri;
    #pragma unroll
    for (int ci = 0; ci < 4; ci++){
      atomicAdd(&ab[(size_t)r*DD + 4*cg + ci], acc[ri][ci]);
    }
  }
}

// ---------------- combine: ki = proj(mf + att@Wo + bo); vsum += w*ki;
//                  zc = normalize(z + c*ki)  (or final output) ----------------
__global__ __launch_bounds__(128) void k_comb(
    const float* __restrict__ z, const float* __restrict__ Wo, const float* __restrict__ bo,
    const float* __restrict__ mf, const float* __restrict__ att,
    float* __restrict__ zc, float* __restrict__ vsum, float* __restrict__ out,
    float wsum, float cretr, int last)
{
  int row = blockIdx.x; int d = threadIdx.x;
  __shared__ float ar[DD]; __shared__ float red[DD];
  ar[d] = att[(size_t)row*DD + d];
  __syncthreads();
  float kur = bo[d];
  #pragma unroll 4
  for (int i = 0; i < DD; i++) kur = fmaf(ar[i], Wo[i*DD + d], kur);
  float zcd = zc[(size_t)row*DD + d];
  float tot = mf[(size_t)row*DD + d] + kur;
  red[d] = tot * zcd; __syncthreads();
  for (int s = 64; s > 0; s >>= 1){ if (d < s) red[d] += red[d+s]; __syncthreads(); }
  float proj = red[0];
  float ki = tot - proj * zcd;
  float vs = vsum[(size_t)row*DD + d] + wsum * ki;
  vsum[(size_t)row*DD + d] = vs;
  float zorig = z[(size_t)row*DD + d];
  float nz = last ? (zorig + vs * (1.0f/6.0f)) : (zorig + cretr * ki);
  __syncthreads();
  red[d] = nz * nz; __syncthreads();
  for (int s = 64; s > 0; s >>= 1){ if (d < s) red[d] += red[d+s]; __syncthreads(); }
  float inv = 1.f / fmaxf(sqrtf(red[0]), 1e-8f);
  float res = nz * inv;
  if (last) out[(size_t)row*DD + d] = res;
  else      zc[(size_t)row*DD + d] = res;
}

extern "C" void kernel_launch(void* const* d_in, const int* in_sizes, int n_in,
                              void* d_out, int out_size, void* d_ws, size_t ws_size,
                              hipStream_t stream) {
  const float* z  = (const float*)d_in[0];
  const float* ck = (const float*)d_in[1];
  const float* cb = (const float*)d_in[2];
  const float* Wq = (const float*)d_in[3];
  const float* bq = (const float*)d_in[4];
  const float* Wk = (const float*)d_in[5];
  const float* bk = (const float*)d_in[6];
  const float* Wo = (const float*)d_in[7];
  const float* bo = (const float*)d_in[8];
  float* out = (float*)d_out;

  float* kh   = (float*)d_ws;          // [B,T,D] k_hat
  float* mf   = kh   + NELT;           // memory_force
  float* zc   = mf   + NELT;           // current stage z
  float* qh   = zc   + NELT;           // q_hat
  float* att  = qh   + NELT;           // attention accumulator
  float* vsum = att  + NELT;           // RK4 weighted sum

  k_prep<<<NROW, 128, 0, stream>>>(z, ck, cb, Wk, bk, kh, mf, zc, vsum);

  const float wv[4] = {1.f, 2.f, 2.f, 1.f};
  const float cv[4] = {0.5f, 0.5f, 1.f, 0.f};
  for (int st = 0; st < 4; st++){
    k_q   <<<NROW, 128, 0, stream>>>(zc, Wq, bq, qh, att);
    k_attn<<<BB*NQT*NSEG, 256, 0, stream>>>(qh, kh, att);
    k_comb<<<NROW, 128, 0, stream>>>(z, Wo, bo, mf, att, zc, vsum, out,
                                     wv[st], cv[st], st == 3);
  }
}

// Round 3
// 546.705 us; speedup vs baseline: 2.8660x; 2.8660x over previous
//
#include <hip/hip_runtime.h>
#include <hip/hip_bf16.h>

#define BB 2
#define TT 4096
#define DD 128
#define KK 256
#define NROW (BB*TT)    // 8192 rows
#define NELT (NROW*DD)  // 1048576 elements per [B,T,D] buffer

typedef __attribute__((ext_vector_type(8))) short short8;
typedef __attribute__((ext_vector_type(4))) float f32x4;

__device__ __forceinline__ short f2bs(float x){
  __hip_bfloat16 h = __float2bfloat16(x);
  return *reinterpret_cast<short*>(&h);
}

// ---------------- prep: k_hat = normalize(z@Wk+bk) -> bf16 [T][D] and [D][T];
//                  memory_force (causal depthwise conv); zc = z; vsum = 0 ----------------
__global__ __launch_bounds__(128) void k_prep(
    const float* __restrict__ z, const float* __restrict__ ck, const float* __restrict__ cb,
    const float* __restrict__ Wk, const float* __restrict__ bk,
    short* __restrict__ khb, short* __restrict__ khT,
    float* __restrict__ mf, float* __restrict__ zc, float* __restrict__ vsum)
{
  int row = blockIdx.x;
  int b = row >> 12;       // row / 4096
  int t = row & 4095;
  int d = threadIdx.x;
  __shared__ float zr[DD];
  __shared__ float red[DD];
  float zv = z[(size_t)row*DD + d];
  zr[d] = zv;
  zc[(size_t)row*DD + d] = zv;
  vsum[(size_t)row*DD + d] = 0.f;
  __syncthreads();
  float a = bk[d];
  #pragma unroll 4
  for (int i = 0; i < DD; i++) a = fmaf(zr[i], Wk[i*DD + d], a);
  red[d] = a*a; __syncthreads();
  for (int s = 64; s > 0; s >>= 1){ if (d < s) red[d] += red[d+s]; __syncthreads(); }
  float inv = 1.f / fmaxf(sqrtf(red[0]), 1e-8f);
  short kv = f2bs(a * inv);
  khb[(size_t)row*DD + d] = kv;
  khT[((size_t)b*DD + d)*TT + t] = kv;   // scattered 2B store, one-shot
  // causal depthwise conv: mf[t,d] = cb[d] + sum_k z[t-(K-1)+k, d] * ck[k,d]
  float c = cb[d];
  const float* zb = z + (size_t)b*TT*DD;
  int kstart = (t >= KK-1) ? 0 : (KK-1-t);
  for (int k = kstart; k < KK; k++){
    int s = t - (KK-1) + k;
    c = fmaf(zb[(size_t)s*DD + d], ck[k*DD + d], c);
  }
  mf[(size_t)row*DD + d] = c;
}

// ---------------- q: q_hat = normalize(zc@Wq+bq) -> bf16; zero att ----------------
__global__ __launch_bounds__(128) void k_q(
    const float* __restrict__ zc, const float* __restrict__ Wq, const float* __restrict__ bq,
    short* __restrict__ qhb, float* __restrict__ att)
{
  int row = blockIdx.x; int d = threadIdx.x;
  __shared__ float zr[DD]; __shared__ float red[DD];
  float zv = zc[(size_t)row*DD + d]; zr[d] = zv;
  att[(size_t)row*DD + d] = 0.f;
  __syncthreads();
  float a = bq[d];
  #pragma unroll 4
  for (int i = 0; i < DD; i++) a = fmaf(zr[i], Wq[i*DD + d], a);
  red[d] = a*a; __syncthreads();
  for (int s = 64; s > 0; s >>= 1){ if (d < s) red[d] += red[d+s]; __syncthreads(); }
  float inv = 1.f / fmaxf(sqrtf(red[0]), 1e-8f);
  qhb[(size_t)row*DD + d] = f2bs(a * inv);
}

// ---------------- MFMA attention: att[t,:] += sum_{s<=t} sin(q_t . k_s) * k_s ----------------
// Q-tile = 64 queries (1 wave : 16 queries). Key range split into 4 segments of 16
// key-tiles (64 keys each); partial results atomicAdd'ed into att.
__global__ __launch_bounds__(256,3) void k_attn2(
    const short* __restrict__ qhb, const short* __restrict__ khb,
    const short* __restrict__ khT, float* __restrict__ att)
{
  int bid = blockIdx.x;
  int seg = bid & 3;
  int qt  = (bid >> 2) & 63;
  int b   = bid >> 8;
  int kt0 = seg * 16;
  if (kt0 > qt) return;            // this q-tile has key-tiles 0..qt only
  int kt1 = min(qt, kt0 + 15);
  int t0 = qt * 64;

  __shared__ __align__(16) short Kb[64*136];   // [key][dim],  row stride 136
  __shared__ __align__(16) short Kt[128*72];   // [dim][key],  row stride 72
  __shared__ __align__(16) float Ps[4][16*68]; // per-wave P,  [q][key], stride 68

  int tid  = threadIdx.x;
  int w    = tid >> 6;
  int lane = tid & 63;
  int n16  = lane & 15;
  int g    = lane >> 4;

  const short* qg  = qhb + (size_t)b*TT*DD;
  const short* kg  = khb + (size_t)b*TT*DD;
  const short* ktg = khT + (size_t)b*DD*TT;

  // persistent Q A-frags: A[m=n16(query)][k=32c+8g+j]
  short8 qa[4];
  {
    const short* qrow = qg + (size_t)(t0 + 16*w + n16)*DD + g*8;
    #pragma unroll
    for (int c = 0; c < 4; c++) qa[c] = *(const short8*)(qrow + 32*c);
  }
  f32x4 acc[8];
  #pragma unroll
  for (int i = 0; i < 8; i++) acc[i] = (f32x4){0.f,0.f,0.f,0.f};

  float* psw = &Ps[w][0];

  for (int kt = kt0; kt <= kt1; kt++){
    int s0 = kt * 64;
    // ---- stage K tile in both layouts (coalesced 16B loads) ----
    #pragma unroll
    for (int it = 0; it < 4; it++){
      int idx = tid + it*256;          // 1024 chunks of 8 bf16
      int r = idx >> 4, c8 = idx & 15;
      *(short8*)(Kb + r*136 + c8*8) = *(const short8*)(kg + (size_t)(s0+r)*DD + c8*8);
    }
    #pragma unroll
    for (int it = 0; it < 4; it++){
      int idx = tid + it*256;
      int r = idx >> 3, c8 = idx & 7;
      *(short8*)(Kt + r*72 + c8*8) = *(const short8*)(ktg + (size_t)r*TT + s0 + c8*8);
    }
    __syncthreads();

    // ---- QK^T: 16 queries x 64 keys ----
    f32x4 s_acc[4];
    #pragma unroll
    for (int n = 0; n < 4; n++) s_acc[n] = (f32x4){0.f,0.f,0.f,0.f};
    #pragma unroll
    for (int c = 0; c < 4; c++){
      #pragma unroll
      for (int n = 0; n < 4; n++){
        short8 bf = *(const short8*)(Kb + (16*n + n16)*136 + 32*c + g*8);
        s_acc[n] = __builtin_amdgcn_mfma_f32_16x16x32_bf16(qa[c], bf, s_acc[n], 0,0,0);
      }
    }
    // ---- sin + causal mask -> Ps (C-layout: col=n16 is key, row=4g+r is query) ----
    int qrow = t0 + 16*w + 4*g;
    #pragma unroll
    for (int n = 0; n < 4; n++){
      int key = s0 + 16*n + n16;
      #pragma unroll
      for (int r = 0; r < 4; r++){
        float v = (key <= qrow + r) ? __sinf(s_acc[n][r]) : 0.f;
        psw[(4*g + r)*68 + 16*n + n16] = v;
      }
    }
    __syncthreads();

    // ---- PV: acc[q][dim] += P[q][key] * K[key][dim] ----
    #pragma unroll
    for (int h = 0; h < 2; h++){
      f32x4 p0 = *(const f32x4*)(psw + n16*68 + 32*h + 8*g);
      f32x4 p1 = *(const f32x4*)(psw + n16*68 + 32*h + 8*g + 4);
      short8 pa;
      pa[0]=f2bs(p0[0]); pa[1]=f2bs(p0[1]); pa[2]=f2bs(p0[2]); pa[3]=f2bs(p0[3]);
      pa[4]=f2bs(p1[0]); pa[5]=f2bs(p1[1]); pa[6]=f2bs(p1[2]); pa[7]=f2bs(p1[3]);
      #pragma unroll
      for (int nt = 0; nt < 8; nt++){
        short8 bf = *(const short8*)(Kt + (16*nt + n16)*72 + 32*h + 8*g);
        acc[nt] = __builtin_amdgcn_mfma_f32_16x16x32_bf16(pa, bf, acc[nt], 0,0,0);
      }
    }
    __syncthreads();
  }

  // ---- epilogue: atomicAdd partial O into att (C-layout: col=n16 is dim) ----
  float* ab = att + ((size_t)b*TT + t0 + 16*w)*DD;
  #pragma unroll
  for (int nt = 0; nt < 8; nt++){
    #pragma unroll
    for (int r = 0; r < 4; r++){
      atomicAdd(&ab[(size_t)(4*g + r)*DD + 16*nt + n16], acc[nt][r]);
    }
  }
}

// ---------------- combine: ki = proj(mf + att@Wo + bo); vsum += w*ki;
//                  zc = normalize(z + c*ki)  (or final output) ----------------
__global__ __launch_bounds__(128) void k_comb(
    const float* __restrict__ z, const float* __restrict__ Wo, const float* __restrict__ bo,
    const float* __restrict__ mf, const float* __restrict__ att,
    float* __restrict__ zc, float* __restrict__ vsum, float* __restrict__ out,
    float wsum, float cretr, int last)
{
  int row = blockIdx.x; int d = threadIdx.x;
  __shared__ float ar[DD]; __shared__ float red[DD];
  ar[d] = att[(size_t)row*DD + d];
  __syncthreads();
  float kur = bo[d];
  #pragma unroll 4
  for (int i = 0; i < DD; i++) kur = fmaf(ar[i], Wo[i*DD + d], kur);
  float zcd = zc[(size_t)row*DD + d];
  float tot = mf[(size_t)row*DD + d] + kur;
  red[d] = tot * zcd; __syncthreads();
  for (int s = 64; s > 0; s >>= 1){ if (d < s) red[d] += red[d+s]; __syncthreads(); }
  float proj = red[0];
  float ki = tot - proj * zcd;
  float vs = vsum[(size_t)row*DD + d] + wsum * ki;
  vsum[(size_t)row*DD + d] = vs;
  float zorig = z[(size_t)row*DD + d];
  float nz = last ? (zorig + vs * (1.0f/6.0f)) : (zorig + cretr * ki);
  __syncthreads();
  red[d] = nz * nz; __syncthreads();
  for (int s = 64; s > 0; s >>= 1){ if (d < s) red[d] += red[d+s]; __syncthreads(); }
  float inv = 1.f / fmaxf(sqrtf(red[0]), 1e-8f);
  float res = nz * inv;
  if (last) out[(size_t)row*DD + d] = res;
  else      zc[(size_t)row*DD + d] = res;
}

extern "C" void kernel_launch(void* const* d_in, const int* in_sizes, int n_in,
                              void* d_out, int out_size, void* d_ws, size_t ws_size,
                              hipStream_t stream) {
  const float* z  = (const float*)d_in[0];
  const float* ck = (const float*)d_in[1];
  const float* cb = (const float*)d_in[2];
  const float* Wq = (const float*)d_in[3];
  const float* bq = (const float*)d_in[4];
  const float* Wk = (const float*)d_in[5];
  const float* bk = (const float*)d_in[6];
  const float* Wo = (const float*)d_in[7];
  const float* bo = (const float*)d_in[8];
  float* out = (float*)d_out;

  float* mf   = (float*)d_ws;          // [B,T,D] f32
  float* zc   = mf   + NELT;
  float* att  = zc   + NELT;
  float* vsum = att  + NELT;
  short* khb  = (short*)(vsum + NELT); // bf16 [B,T,D]
  short* khT  = khb  + NELT;           // bf16 [B,D,T]
  short* qhb  = khT  + NELT;           // bf16 [B,T,D]

  k_prep<<<NROW, 128, 0, stream>>>(z, ck, cb, Wk, bk, khb, khT, mf, zc, vsum);

  const float wv[4] = {1.f, 2.f, 2.f, 1.f};
  const float cv[4] = {0.5f, 0.5f, 1.f, 0.f};
  for (int st = 0; st < 4; st++){
    k_q    <<<NROW, 128, 0, stream>>>(zc, Wq, bq, qhb, att);
    k_attn2<<<BB*64*4, 256, 0, stream>>>(qhb, khb, khT, att);
    k_comb <<<NROW, 128, 0, stream>>>(z, Wo, bo, mf, att, zc, vsum, out,
                                      wv[st], cv[st], st == 3);
  }
}

// Round 4
// 331.887 us; speedup vs baseline: 4.7211x; 1.6473x over previous
//
#include <hip/hip_runtime.h>
#include <hip/hip_bf16.h>

#define BB 2
#define TT 4096
#define DD 128
#define KK 256
#define NROW (BB*TT)    // 8192 rows
#define NELT (NROW*DD)  // 1048576 elements per [B,T,D] buffer

typedef _Float16 f16;
typedef __attribute__((ext_vector_type(8))) f16 half8;
typedef __attribute__((ext_vector_type(4))) float f32x4;

// ================= k_proj: k_hat = normalize(z@Wk+bk) -> fp16 [T][D] and [D][T] =================
// 32 rows/block, Wk staged in LDS, 2 rows x 8 dims per thread.
__global__ __launch_bounds__(256) void k_proj(
    const float* __restrict__ z, const float* __restrict__ Wk, const float* __restrict__ bk,
    f16* __restrict__ khb, f16* __restrict__ khT)
{
  __shared__ float Ws[DD*DD];
  __shared__ float zs[32*DD];
  int tid = threadIdx.x;
  int r0 = blockIdx.x * 32;
  #pragma unroll
  for (int it = 0; it < 16; it++){
    int idx = tid + it*256;
    *(f32x4*)(Ws + idx*4) = *(const f32x4*)(Wk + (size_t)idx*4);
  }
  #pragma unroll
  for (int it = 0; it < 4; it++){
    int idx = tid + it*256;
    *(f32x4*)(zs + idx*4) = *(const f32x4*)(z + (size_t)r0*DD + idx*4);
  }
  __syncthreads();
  int c = tid & 15, rr = tid >> 4;
  float acc0[8], acc1[8];
  #pragma unroll
  for (int u = 0; u < 8; u++){ float bv = bk[c*8+u]; acc0[u] = bv; acc1[u] = bv; }
  const float* zr0 = zs + rr*DD;
  const float* zr1 = zs + (rr+16)*DD;
  #pragma unroll 4
  for (int i = 0; i < DD; i++){
    f32x4 w0 = *(const f32x4*)(Ws + i*DD + c*8);
    f32x4 w1 = *(const f32x4*)(Ws + i*DD + c*8 + 4);
    float a0 = zr0[i], a1 = zr1[i];
    #pragma unroll
    for (int u = 0; u < 4; u++){
      acc0[u]   = fmaf(a0, w0[u], acc0[u]);   acc1[u]   = fmaf(a1, w0[u], acc1[u]);
      acc0[4+u] = fmaf(a0, w1[u], acc0[4+u]); acc1[4+u] = fmaf(a1, w1[u], acc1[4+u]);
    }
  }
  float s0 = 0.f, s1 = 0.f;
  #pragma unroll
  for (int u = 0; u < 8; u++){ s0 = fmaf(acc0[u], acc0[u], s0); s1 = fmaf(acc1[u], acc1[u], s1); }
  #pragma unroll
  for (int m = 1; m < 16; m <<= 1){ s0 += __shfl_xor(s0, m, 16); s1 += __shfl_xor(s1, m, 16); }
  float inv0 = 1.f / fmaxf(sqrtf(s0), 1e-8f);
  float inv1 = 1.f / fmaxf(sqrtf(s1), 1e-8f);
  half8 h0, h1;
  #pragma unroll
  for (int u = 0; u < 8; u++){ h0[u] = (f16)(acc0[u]*inv0); h1[u] = (f16)(acc1[u]*inv1); }
  int row0 = r0 + rr, row1 = row0 + 16;
  *(half8*)(khb + (size_t)row0*DD + c*8) = h0;
  *(half8*)(khb + (size_t)row1*DD + c*8) = h1;
  int b = row0 >> 12, t0 = row0 & 4095, t1 = row1 & 4095;
  #pragma unroll
  for (int u = 0; u < 8; u++){
    khT[((size_t)b*DD + c*8 + u)*TT + t0] = h0[u];
    khT[((size_t)b*DD + c*8 + u)*TT + t1] = h1[u];
  }
}

// ================= k_conv: causal depthwise conv, register sliding window =================
// thread: one d, 8 consecutive t. Rolling 8-deep ck queue; 2 loads per 8 FMAs.
__global__ __launch_bounds__(256) void k_conv(
    const float* __restrict__ z, const float* __restrict__ ck, const float* __restrict__ cb,
    float* __restrict__ mf)
{
  int tid = threadIdx.x;
  int d = tid & 127, tg = tid >> 7;
  int bid = blockIdx.x;
  int b = bid >> 8;
  int tbase = ((bid & 255) << 4) + tg*8;
  const float* zb = z + (size_t)b*TT*DD;
  float acc[8];
  #pragma unroll
  for (int j = 0; j < 8; j++) acc[j] = 0.f;
  float ckq[8];
  #pragma unroll
  for (int u = 0; u < 8; u++) ckq[u] = 0.f;
  int sstart = tbase - (KK-1);
  for (int ch = 0; ch < 33; ch++){
    #pragma unroll
    for (int u = 0; u < 8; u++){
      int base = ch*8 + u;
      int s = sstart + base;
      float zv = ((unsigned)s < (unsigned)TT && base < 263) ? zb[(size_t)s*DD + d] : 0.f;
      ckq[u] = (base < KK) ? ck[(size_t)base*DD + d] : 0.f;
      #pragma unroll
      for (int j = 0; j < 8; j++) acc[j] = fmaf(ckq[(u-j)&7], zv, acc[j]);
    }
  }
  float cbv = cb[d];
  #pragma unroll
  for (int j = 0; j < 8; j++)
    mf[((size_t)b*TT + tbase + j)*DD + d] = acc[j] + cbv;
}

// ================= k_q: q_hat = normalize(zcur@Wq+bq) -> fp16; zero att =================
__global__ __launch_bounds__(256) void k_q(
    const float* __restrict__ zcur, const float* __restrict__ Wq, const float* __restrict__ bq,
    f16* __restrict__ qhb, float* __restrict__ att)
{
  __shared__ float Ws[DD*DD];
  __shared__ float zs[32*DD];
  int tid = threadIdx.x;
  int r0 = blockIdx.x * 32;
  #pragma unroll
  for (int it = 0; it < 16; it++){
    int idx = tid + it*256;
    *(f32x4*)(Ws + idx*4) = *(const f32x4*)(Wq + (size_t)idx*4);
  }
  #pragma unroll
  for (int it = 0; it < 4; it++){
    int idx = tid + it*256;
    *(f32x4*)(zs + idx*4) = *(const f32x4*)(zcur + (size_t)r0*DD + idx*4);
    *(f32x4*)(att + (size_t)r0*DD + idx*4) = (f32x4){0.f,0.f,0.f,0.f};
  }
  __syncthreads();
  int c = tid & 15, rr = tid >> 4;
  float acc0[8], acc1[8];
  #pragma unroll
  for (int u = 0; u < 8; u++){ float bv = bq[c*8+u]; acc0[u] = bv; acc1[u] = bv; }
  const float* zr0 = zs + rr*DD;
  const float* zr1 = zs + (rr+16)*DD;
  #pragma unroll 4
  for (int i = 0; i < DD; i++){
    f32x4 w0 = *(const f32x4*)(Ws + i*DD + c*8);
    f32x4 w1 = *(const f32x4*)(Ws + i*DD + c*8 + 4);
    float a0 = zr0[i], a1 = zr1[i];
    #pragma unroll
    for (int u = 0; u < 4; u++){
      acc0[u]   = fmaf(a0, w0[u], acc0[u]);   acc1[u]   = fmaf(a1, w0[u], acc1[u]);
      acc0[4+u] = fmaf(a0, w1[u], acc0[4+u]); acc1[4+u] = fmaf(a1, w1[u], acc1[4+u]);
    }
  }
  float s0 = 0.f, s1 = 0.f;
  #pragma unroll
  for (int u = 0; u < 8; u++){ s0 = fmaf(acc0[u], acc0[u], s0); s1 = fmaf(acc1[u], acc1[u], s1); }
  #pragma unroll
  for (int m = 1; m < 16; m <<= 1){ s0 += __shfl_xor(s0, m, 16); s1 += __shfl_xor(s1, m, 16); }
  float inv0 = 1.f / fmaxf(sqrtf(s0), 1e-8f);
  float inv1 = 1.f / fmaxf(sqrtf(s1), 1e-8f);
  half8 h0, h1;
  #pragma unroll
  for (int u = 0; u < 8; u++){ h0[u] = (f16)(acc0[u]*inv0); h1[u] = (f16)(acc1[u]*inv1); }
  *(half8*)(qhb + (size_t)(r0+rr)*DD + c*8) = h0;
  *(half8*)(qhb + (size_t)(r0+rr+16)*DD + c*8) = h1;
}

// ================= MFMA attention (fp16): att[t,:] += sum_{s<=t} sin(q_t.k_s) k_s =================
__global__ __launch_bounds__(256,3) void k_attn2(
    const f16* __restrict__ qhb, const f16* __restrict__ khb,
    const f16* __restrict__ khT, float* __restrict__ att)
{
  int bid = blockIdx.x;
  int seg = bid & 3;
  int qt  = (bid >> 2) & 63;
  int b   = bid >> 8;
  int kt0 = seg * 16;
  if (kt0 > qt) return;
  int kt1 = min(qt, kt0 + 15);
  int t0 = qt * 64;

  __shared__ __align__(16) f16 Kb[64*136];     // [key][dim],  stride 136
  __shared__ __align__(16) f16 Kt[128*72];     // [dim][key],  stride 72
  __shared__ __align__(16) float Ps[4][16*68]; // per-wave P,  [q][key], stride 68

  int tid  = threadIdx.x;
  int w    = tid >> 6;
  int lane = tid & 63;
  int n16  = lane & 15;
  int g    = lane >> 4;

  const f16* qg  = qhb + (size_t)b*TT*DD;
  const f16* kg  = khb + (size_t)b*TT*DD;
  const f16* ktg = khT + (size_t)b*DD*TT;

  half8 qa[4];
  {
    const f16* qrow = qg + (size_t)(t0 + 16*w + n16)*DD + g*8;
    #pragma unroll
    for (int c = 0; c < 4; c++) qa[c] = *(const half8*)(qrow + 32*c);
  }
  f32x4 acc[8];
  #pragma unroll
  for (int i = 0; i < 8; i++) acc[i] = (f32x4){0.f,0.f,0.f,0.f};

  float* psw = &Ps[w][0];

  for (int kt = kt0; kt <= kt1; kt++){
    int s0 = kt * 64;
    #pragma unroll
    for (int it = 0; it < 4; it++){
      int idx = tid + it*256;
      int r = idx >> 4, c8 = idx & 15;
      *(half8*)(Kb + r*136 + c8*8) = *(const half8*)(kg + (size_t)(s0+r)*DD + c8*8);
    }
    #pragma unroll
    for (int it = 0; it < 4; it++){
      int idx = tid + it*256;
      int r = idx >> 3, c8 = idx & 7;
      *(half8*)(Kt + r*72 + c8*8) = *(const half8*)(ktg + (size_t)r*TT + s0 + c8*8);
    }
    __syncthreads();

    // QK^T
    f32x4 s_acc[4];
    #pragma unroll
    for (int n = 0; n < 4; n++) s_acc[n] = (f32x4){0.f,0.f,0.f,0.f};
    #pragma unroll
    for (int c = 0; c < 4; c++){
      #pragma unroll
      for (int n = 0; n < 4; n++){
        half8 bf = *(const half8*)(Kb + (16*n + n16)*136 + 32*c + g*8);
        s_acc[n] = __builtin_amdgcn_mfma_f32_16x16x32_f16(qa[c], bf, s_acc[n], 0,0,0);
      }
    }
    // sin + causal mask -> Ps
    int qrow = t0 + 16*w + 4*g;
    #pragma unroll
    for (int n = 0; n < 4; n++){
      int key = s0 + 16*n + n16;
      #pragma unroll
      for (int r = 0; r < 4; r++){
        float v = (key <= qrow + r) ? __sinf(s_acc[n][r]) : 0.f;
        psw[(4*g + r)*68 + 16*n + n16] = v;
      }
    }
    __syncthreads();

    // PV
    #pragma unroll
    for (int h = 0; h < 2; h++){
      f32x4 p0 = *(const f32x4*)(psw + n16*68 + 32*h + 8*g);
      f32x4 p1 = *(const f32x4*)(psw + n16*68 + 32*h + 8*g + 4);
      half8 pa;
      pa[0]=(f16)p0[0]; pa[1]=(f16)p0[1]; pa[2]=(f16)p0[2]; pa[3]=(f16)p0[3];
      pa[4]=(f16)p1[0]; pa[5]=(f16)p1[1]; pa[6]=(f16)p1[2]; pa[7]=(f16)p1[3];
      #pragma unroll
      for (int nt = 0; nt < 8; nt++){
        half8 bf = *(const half8*)(Kt + (16*nt + n16)*72 + 32*h + 8*g);
        acc[nt] = __builtin_amdgcn_mfma_f32_16x16x32_f16(pa, bf, acc[nt], 0,0,0);
      }
    }
    __syncthreads();
  }

  float* ab = att + ((size_t)b*TT + t0 + 16*w)*DD;
  #pragma unroll
  for (int nt = 0; nt < 8; nt++){
    #pragma unroll
    for (int r = 0; r < 4; r++){
      atomicAdd(&ab[(size_t)(4*g + r)*DD + 16*nt + n16], acc[nt][r]);
    }
  }
}

// ================= k_comb: ki = proj(mf + att@Wo + bo); vsum += w*ki; retract =================
__global__ __launch_bounds__(256) void k_comb(
    const float* __restrict__ z, const float* __restrict__ Wo, const float* __restrict__ bo,
    const float* __restrict__ mf, const float* __restrict__ att,
    const float* __restrict__ zin, float* __restrict__ zout,
    float* __restrict__ vsum, float* __restrict__ out,
    float wsum, float cretr, int first, int last)
{
  __shared__ float Ws[DD*DD];
  __shared__ float As[32*DD];
  int tid = threadIdx.x;
  int r0 = blockIdx.x * 32;
  #pragma unroll
  for (int it = 0; it < 16; it++){
    int idx = tid + it*256;
    *(f32x4*)(Ws + idx*4) = *(const f32x4*)(Wo + (size_t)idx*4);
  }
  #pragma unroll
  for (int it = 0; it < 4; it++){
    int idx = tid + it*256;
    *(f32x4*)(As + idx*4) = *(const f32x4*)(att + (size_t)r0*DD + idx*4);
  }
  __syncthreads();
  int c = tid & 15, rr = tid >> 4;
  float kur0[8], kur1[8];
  #pragma unroll
  for (int u = 0; u < 8; u++){ float bv = bo[c*8+u]; kur0[u] = bv; kur1[u] = bv; }
  const float* ar0 = As + rr*DD;
  const float* ar1 = As + (rr+16)*DD;
  #pragma unroll 4
  for (int i = 0; i < DD; i++){
    f32x4 w0 = *(const f32x4*)(Ws + i*DD + c*8);
    f32x4 w1 = *(const f32x4*)(Ws + i*DD + c*8 + 4);
    float a0 = ar0[i], a1 = ar1[i];
    #pragma unroll
    for (int u = 0; u < 4; u++){
      kur0[u]   = fmaf(a0, w0[u], kur0[u]);   kur1[u]   = fmaf(a1, w0[u], kur1[u]);
      kur0[4+u] = fmaf(a0, w1[u], kur0[4+u]); kur1[4+u] = fmaf(a1, w1[u], kur1[4+u]);
    }
  }
  size_t o0 = (size_t)(r0+rr)*DD + c*8;
  size_t o1 = (size_t)(r0+rr+16)*DD + c*8;
  float tot0[8], tot1[8], zi0[8], zi1[8];
  {
    f32x4 m0a = *(const f32x4*)(mf + o0), m0b = *(const f32x4*)(mf + o0 + 4);
    f32x4 m1a = *(const f32x4*)(mf + o1), m1b = *(const f32x4*)(mf + o1 + 4);
    f32x4 z0a = *(const f32x4*)(zin + o0), z0b = *(const f32x4*)(zin + o0 + 4);
    f32x4 z1a = *(const f32x4*)(zin + o1), z1b = *(const f32x4*)(zin + o1 + 4);
    #pragma unroll
    for (int u = 0; u < 4; u++){
      tot0[u] = m0a[u] + kur0[u]; tot0[4+u] = m0b[u] + kur0[4+u];
      tot1[u] = m1a[u] + kur1[u]; tot1[4+u] = m1b[u] + kur1[4+u];
      zi0[u] = z0a[u]; zi0[4+u] = z0b[u];
      zi1[u] = z1a[u]; zi1[4+u] = z1b[u];
    }
  }
  float p0 = 0.f, p1 = 0.f;
  #pragma unroll
  for (int u = 0; u < 8; u++){ p0 = fmaf(tot0[u], zi0[u], p0); p1 = fmaf(tot1[u], zi1[u], p1); }
  #pragma unroll
  for (int m = 1; m < 16; m <<= 1){ p0 += __shfl_xor(p0, m, 16); p1 += __shfl_xor(p1, m, 16); }
  float ki0[8], ki1[8], vs0[8], vs1[8];
  #pragma unroll
  for (int u = 0; u < 8; u++){
    ki0[u] = tot0[u] - p0 * zi0[u];
    ki1[u] = tot1[u] - p1 * zi1[u];
  }
  if (first){
    #pragma unroll
    for (int u = 0; u < 8; u++){ vs0[u] = wsum*ki0[u]; vs1[u] = wsum*ki1[u]; }
  } else {
    f32x4 v0a = *(const f32x4*)(vsum + o0), v0b = *(const f32x4*)(vsum + o0 + 4);
    f32x4 v1a = *(const f32x4*)(vsum + o1), v1b = *(const f32x4*)(vsum + o1 + 4);
    #pragma unroll
    for (int u = 0; u < 4; u++){
      vs0[u] = fmaf(wsum, ki0[u], v0a[u]); vs0[4+u] = fmaf(wsum, ki0[4+u], v0b[u]);
      vs1[u] = fmaf(wsum, ki1[u], v1a[u]); vs1[4+u] = fmaf(wsum, ki1[4+u], v1b[u]);
    }
  }
  if (!last){
    f32x4 va = {vs0[0],vs0[1],vs0[2],vs0[3]}, vb = {vs0[4],vs0[5],vs0[6],vs0[7]};
    f32x4 vc = {vs1[0],vs1[1],vs1[2],vs1[3]}, vd = {vs1[4],vs1[5],vs1[6],vs1[7]};
    *(f32x4*)(vsum + o0) = va; *(f32x4*)(vsum + o0 + 4) = vb;
    *(f32x4*)(vsum + o1) = vc; *(f32x4*)(vsum + o1 + 4) = vd;
  }
  float nz0[8], nz1[8];
  {
    f32x4 z0a = *(const f32x4*)(z + o0), z0b = *(const f32x4*)(z + o0 + 4);
    f32x4 z1a = *(const f32x4*)(z + o1), z1b = *(const f32x4*)(z + o1 + 4);
    #pragma unroll
    for (int u = 0; u < 4; u++){
      float d0a = last ? vs0[u]*(1.f/6.f)   : cretr*ki0[u];
      float d0b = last ? vs0[4+u]*(1.f/6.f) : cretr*ki0[4+u];
      float d1a = last ? vs1[u]*(1.f/6.f)   : cretr*ki1[u];
      float d1b = last ? vs1[4+u]*(1.f/6.f) : cretr*ki1[4+u];
      nz0[u] = z0a[u] + d0a; nz0[4+u] = z0b[u] + d0b;
      nz1[u] = z1a[u] + d1a; nz1[4+u] = z1b[u] + d1b;
    }
  }
  float n0 = 0.f, n1 = 0.f;
  #pragma unroll
  for (int u = 0; u < 8; u++){ n0 = fmaf(nz0[u], nz0[u], n0); n1 = fmaf(nz1[u], nz1[u], n1); }
  #pragma unroll
  for (int m = 1; m < 16; m <<= 1){ n0 += __shfl_xor(n0, m, 16); n1 += __shfl_xor(n1, m, 16); }
  float i0 = 1.f / fmaxf(sqrtf(n0), 1e-8f);
  float i1 = 1.f / fmaxf(sqrtf(n1), 1e-8f);
  float* dst = last ? out : zout;
  f32x4 ra = {nz0[0]*i0, nz0[1]*i0, nz0[2]*i0, nz0[3]*i0};
  f32x4 rb = {nz0[4]*i0, nz0[5]*i0, nz0[6]*i0, nz0[7]*i0};
  f32x4 rc = {nz1[0]*i1, nz1[1]*i1, nz1[2]*i1, nz1[3]*i1};
  f32x4 rd = {nz1[4]*i1, nz1[5]*i1, nz1[6]*i1, nz1[7]*i1};
  *(f32x4*)(dst + o0) = ra; *(f32x4*)(dst + o0 + 4) = rb;
  *(f32x4*)(dst + o1) = rc; *(f32x4*)(dst + o1 + 4) = rd;
}

extern "C" void kernel_launch(void* const* d_in, const int* in_sizes, int n_in,
                              void* d_out, int out_size, void* d_ws, size_t ws_size,
                              hipStream_t stream) {
  const float* z  = (const float*)d_in[0];
  const float* ck = (const float*)d_in[1];
  const float* cb = (const float*)d_in[2];
  const float* Wq = (const float*)d_in[3];
  const float* bq = (const float*)d_in[4];
  const float* Wk = (const float*)d_in[5];
  const float* bk = (const float*)d_in[6];
  const float* Wo = (const float*)d_in[7];
  const float* bo = (const float*)d_in[8];
  float* out = (float*)d_out;

  float* mf   = (float*)d_ws;          // [B,T,D] f32
  float* zc   = mf   + NELT;
  float* att  = zc   + NELT;
  float* vsum = att  + NELT;
  f16*   khb  = (f16*)(vsum + NELT);   // fp16 [B,T,D]
  f16*   khT  = khb  + NELT;           // fp16 [B,D,T]
  f16*   qhb  = khT  + NELT;           // fp16 [B,T,D]

  k_proj<<<NROW/32, 256, 0, stream>>>(z, Wk, bk, khb, khT);
  k_conv<<<BB*TT/16, 256, 0, stream>>>(z, ck, cb, mf);

  const float wv[4] = {1.f, 2.f, 2.f, 1.f};
  const float cv[4] = {0.5f, 0.5f, 1.f, 0.f};
  for (int st = 0; st < 4; st++){
    const float* zcur = (st == 0) ? z : zc;
    k_q    <<<NROW/32, 256, 0, stream>>>(zcur, Wq, bq, qhb, att);
    k_attn2<<<BB*64*4, 256, 0, stream>>>(qhb, khb, khT, att);
    k_comb <<<NROW/32, 256, 0, stream>>>(z, Wo, bo, mf, att, zcur, zc, vsum, out,
                                         wv[st], cv[st], st == 0, st == 3);
  }
}